// Round 3
// baseline (467.603 us; speedup 1.0000x reference)
//
#include <hip/hip_runtime.h>

// Problem dims (fixed by the reference): B=256, T=100, D=1024, H=128, C=5
constexpr int Bsz = 256;
constexpr int Tn  = 100;
constexpr int Dn  = 1024;
constexpr int Hn  = 128;
constexpr int Cn  = 5;

// float64 values of np.exp(-1/10), np.exp(-1/20)
#define D1 0.9048374180359595731642491
#define D2 0.9512294245007140090914253

// ---------------------------------------------------------------------------
// Phase 1: Hc[r,128] = X[row(r),1024] @ W1[1024,128]   (fp64 accumulate)
// TILE 16(M) x 128(N), BK=16, 128 threads (2 waves). Per-thread 4x4 f64 tile;
// wave w owns N-half w*64..w*64+64. f32->f64 convert once at staging.
// LDS: A [m][k] padded row 18 (2-way banks only); B in 4-col groups padded
// to 6 f64 (48B, b128-aligned, 2-way banks only).
// ---------------------------------------------------------------------------
constexpr int TILE_M = 16;
constexpr int BK     = 16;
constexpr int AP     = BK + 2;        // 18 f64 per A row (144B, 16B-aligned)
constexpr int BGRP   = 6;             // 4 cols + 2 pad
constexpr int BROW   = 32 * BGRP;     // 192 f64 per B k-row

__global__ __launch_bounds__(128) void gemm_xw1_f64(
    const float* __restrict__ X, const float* __restrict__ W1,
    double* __restrict__ Hc, int t0, int Tc)
{
  __shared__ double At[TILE_M][AP];   // [m][k]
  __shared__ double Bs[BK][BROW];     // [k][group*6 + pos]

  const int tid = threadIdx.x;
  const int m0  = blockIdx.x * TILE_M;

  // staging assignments
  const int rowA = tid >> 3;          // 0..15
  const int ka   = (tid & 7) * 2;     // k-pair within chunk
  const int kB   = tid >> 5;          // 0..3
  const int g2   = tid & 31;          // B col-group (4 cols)

  // compute assignments
  const int w    = tid >> 6;          // wave: N-half
  const int lane = tid & 63;
  const int ml   = lane >> 4;         // rows ml*4 .. +4
  const int nc   = lane & 15;         // cols w*64 + nc*4
  const int gr   = w * 16 + nc;       // B read group

  // chunk-row -> global X row
  const int rc   = m0 + rowA;
  const int bidx = rc / Tc;
  const int tl   = rc - bidx * Tc;
  const int grow = bidx * Tn + t0 + tl;

  const float* Apt = X  + (size_t)grow * Dn + ka;
  const float* Bpt = W1 + (size_t)kB * Hn + g2 * 4;

  double acc[4][4];
  #pragma unroll
  for (int i = 0; i < 4; ++i)
    #pragma unroll
    for (int j = 0; j < 4; ++j) acc[i][j] = 0.0;

  // register prefetch of chunk 0
  float2 pa  = *(const float2*)Apt;
  float4 pb0 = *(const float4*)(Bpt + (size_t)0 * 4 * Hn);
  float4 pb1 = *(const float4*)(Bpt + (size_t)1 * 4 * Hn);
  float4 pb2 = *(const float4*)(Bpt + (size_t)2 * 4 * Hn);
  float4 pb3 = *(const float4*)(Bpt + (size_t)3 * 4 * Hn);

  constexpr int NC = Dn / BK;         // 64 K-chunks
  for (int c = 0; c < NC; ++c) {
    __syncthreads();
    {   // A: one double2 store (b128)
      double2 ad; ad.x = (double)pa.x; ad.y = (double)pa.y;
      *(double2*)&At[rowA][ka] = ad;
    }
    {   // B: 4 k-rows x 4 cols, two b128 stores each
      double2 u, v;
      u.x=(double)pb0.x; u.y=(double)pb0.y; v.x=(double)pb0.z; v.y=(double)pb0.w;
      *(double2*)&Bs[kB +  0][g2*BGRP] = u; *(double2*)&Bs[kB +  0][g2*BGRP+2] = v;
      u.x=(double)pb1.x; u.y=(double)pb1.y; v.x=(double)pb1.z; v.y=(double)pb1.w;
      *(double2*)&Bs[kB +  4][g2*BGRP] = u; *(double2*)&Bs[kB +  4][g2*BGRP+2] = v;
      u.x=(double)pb2.x; u.y=(double)pb2.y; v.x=(double)pb2.z; v.y=(double)pb2.w;
      *(double2*)&Bs[kB +  8][g2*BGRP] = u; *(double2*)&Bs[kB +  8][g2*BGRP+2] = v;
      u.x=(double)pb3.x; u.y=(double)pb3.y; v.x=(double)pb3.z; v.y=(double)pb3.w;
      *(double2*)&Bs[kB + 12][g2*BGRP] = u; *(double2*)&Bs[kB + 12][g2*BGRP+2] = v;
    }
    __syncthreads();

    if (c + 1 < NC) {                 // prefetch next chunk
      const int k0 = (c + 1) * BK;
      pa  = *(const float2*)(Apt + k0);
      pb0 = *(const float4*)(Bpt + (size_t)(k0 +  0) * Hn);
      pb1 = *(const float4*)(Bpt + (size_t)(k0 +  4) * Hn);
      pb2 = *(const float4*)(Bpt + (size_t)(k0 +  8) * Hn);
      pb3 = *(const float4*)(Bpt + (size_t)(k0 + 12) * Hn);
    }

    #pragma unroll
    for (int kq = 0; kq < BK; kq += 4) {
      double ar[4][4];                // 4 rows x 4 k in registers
      #pragma unroll
      for (int r = 0; r < 4; ++r) {
        double2 x0 = *(const double2*)&At[ml*4 + r][kq];
        double2 x1 = *(const double2*)&At[ml*4 + r][kq + 2];
        ar[r][0] = x0.x; ar[r][1] = x0.y; ar[r][2] = x1.x; ar[r][3] = x1.y;
      }
      #pragma unroll
      for (int q = 0; q < 4; ++q) {
        double2 b01 = *(const double2*)&Bs[kq + q][gr*BGRP];
        double2 b23 = *(const double2*)&Bs[kq + q][gr*BGRP + 2];
        const double bv0 = b01.x, bv1 = b01.y, bv2 = b23.x, bv3 = b23.y;
        #pragma unroll
        for (int r = 0; r < 4; ++r) {
          acc[r][0] = fma(ar[r][q], bv0, acc[r][0]);
          acc[r][1] = fma(ar[r][q], bv1, acc[r][1]);
          acc[r][2] = fma(ar[r][q], bv2, acc[r][2]);
          acc[r][3] = fma(ar[r][q], bv3, acc[r][3]);
        }
      }
    }
  }

  #pragma unroll
  for (int r = 0; r < 4; ++r) {
    double* orow = Hc + (size_t)(m0 + ml*4 + r) * Hn + w*64 + nc*4;
    double2 o0; o0.x = acc[r][0]; o0.y = acc[r][1];
    double2 o1; o1.x = acc[r][2]; o1.y = acc[r][3];
    *(double2*)orow       = o0;
    *(double2*)(orow + 2) = o1;
  }
}

// ---------------------------------------------------------------------------
// Phase 2: per-batch-row LIF scan over t in [t0, t0+Tc), fp64 state in ws.
// One 64-lane wave per batch row; each lane owns 2 hidden neurons.
// ---------------------------------------------------------------------------
__global__ __launch_bounds__(64) void snn_scan_f64(
    const double* __restrict__ Hc, const float* __restrict__ b1,
    const float* __restrict__ W2, const float* __restrict__ b2,
    double* __restrict__ v1s, double* __restrict__ v2s,
    double* __restrict__ accs, float* __restrict__ out, int t0, int Tc)
{
#pragma clang fp contract(off)
  const int b    = blockIdx.x;
  const int lane = threadIdx.x;
  const int j0   = lane * 2;

  double w2a[Cn], w2b[Cn], bb2[Cn];
  #pragma unroll
  for (int c = 0; c < Cn; ++c) {
    w2a[c] = (double)W2[(size_t)j0 * Cn + c];
    w2b[c] = (double)W2[(size_t)(j0 + 1) * Cn + c];
    bb2[c] = (double)b2[c];
  }
  const double b1a = (double)b1[j0];
  const double b1b = (double)b1[j0 + 1];

  double v1a, v1b, v2[Cn], acc[Cn];
  if (t0 == 0) {
    v1a = 0.0; v1b = 0.0;
    #pragma unroll
    for (int c = 0; c < Cn; ++c) { v2[c] = 0.0; acc[c] = 0.0; }
  } else {
    v1a = v1s[(size_t)b * Hn + j0];
    v1b = v1s[(size_t)b * Hn + j0 + 1];
    #pragma unroll
    for (int c = 0; c < Cn; ++c) {
      v2[c]  = v2s[(size_t)b * Cn + c];
      acc[c] = accs[(size_t)b * Cn + c];
    }
  }

  const double* hp = Hc + (size_t)b * Tc * Hn + j0;
  double2 hnext = *(const double2*)hp;

  for (int t = 0; t < Tc; ++t) {
    const double2 hc = hnext;
    const int tn = (t + 1 < Tc) ? (t + 1) : t;
    hnext = *(const double2*)(hp + (size_t)tn * Hn);

    // v1 = (v1*d1 + h) + b1  (left-assoc, separate roundings)
    v1a = (v1a * D1 + hc.x) + b1a;
    v1b = (v1b * D1 + hc.y) + b1b;
    const double s1a = (v1a >= 1.0) ? 1.0 : 0.0;
    const double s1b = (v1b >= 1.0) ? 1.0 : 0.0;
    v1a = (v1a >= 1.0) ? 0.0 : v1a;
    v1b = (v1b >= 1.0) ? 0.0 : v1b;

    // p[c] = sum_j s1[j] * W2[j,c]  (fp64 butterfly)
    double p[Cn];
    #pragma unroll
    for (int c = 0; c < Cn; ++c)
      p[c] = s1a * w2a[c] + s1b * w2b[c];
    #pragma unroll
    for (int off = 32; off > 0; off >>= 1) {
      #pragma unroll
      for (int c = 0; c < Cn; ++c)
        p[c] += __shfl_xor(p[c], off);
    }

    // v2 = ((v2*d2) + p) + b2
    #pragma unroll
    for (int c = 0; c < Cn; ++c) {
      const double v = ((v2[c] * D2) + p[c]) + bb2[c];
      const double s2 = (v >= 1.0) ? 1.0 : 0.0;
      v2[c]  = (v >= 1.0) ? 0.0 : v;
      acc[c] += s2;
    }
  }

  // persist state for next chunk
  v1s[(size_t)b * Hn + j0]     = v1a;
  v1s[(size_t)b * Hn + j0 + 1] = v1b;
  if (lane == 0) {
    #pragma unroll
    for (int c = 0; c < Cn; ++c) {
      v2s[(size_t)b * Cn + c]  = v2[c];
      accs[(size_t)b * Cn + c] = acc[c];
    }
    if (t0 + Tc == Tn) {
      #pragma unroll
      for (int c = 0; c < Cn; ++c)
        out[(size_t)b * Cn + c] = (float)(acc[c] / 100.0);
    }
  }
}

// ---------------------------------------------------------------------------
extern "C" void kernel_launch(void* const* d_in, const int* in_sizes, int n_in,
                              void* d_out, int out_size, void* d_ws, size_t ws_size,
                              hipStream_t stream) {
  const float* X  = (const float*)d_in[0];   // [B,T,D]
  const float* W1 = (const float*)d_in[1];   // [D,H]
  const float* b1 = (const float*)d_in[2];   // [H]
  const float* W2 = (const float*)d_in[3];   // [H,C]
  const float* b2 = (const float*)d_in[4];   // [C]
  float* out = (float*)d_out;                // [B,C]

  // pick largest T-chunk whose h-buffer + state fits in ws
  const size_t stateDoubles = (size_t)Bsz * Hn + 2 * (size_t)Bsz * Cn;
  static const int cands[] = {100, 50, 25, 20, 10, 5, 4, 2, 1};
  int Tc = 1;
  for (int i = 0; i < 9; ++i) {
    const size_t need = ((size_t)Bsz * cands[i] * Hn + stateDoubles) * sizeof(double);
    if (need <= ws_size) { Tc = cands[i]; break; }
  }

  double* Hc   = (double*)d_ws;                      // [B*Tc, H]
  double* v1s  = Hc  + (size_t)Bsz * Tc * Hn;        // [B, H]
  double* v2s  = v1s + (size_t)Bsz * Hn;             // [B, C]
  double* accs = v2s + (size_t)Bsz * Cn;             // [B, C]

  for (int t0 = 0; t0 < Tn; t0 += Tc) {
    gemm_xw1_f64<<<dim3((Bsz * Tc) / TILE_M), dim3(128), 0, stream>>>(X, W1, Hc, t0, Tc);
    snn_scan_f64<<<dim3(Bsz), dim3(64), 0, stream>>>(Hc, b1, W2, b2,
                                                     v1s, v2s, accs, out, t0, Tc);
  }
}

// Round 5
// 405.930 us; speedup vs baseline: 1.1519x; 1.1519x over previous
//
#include <hip/hip_runtime.h>

// Problem dims (fixed by the reference): B=256, T=100, D=1024, H=128, C=5
constexpr int Bsz = 256;
constexpr int Tn  = 100;
constexpr int Dn  = 1024;
constexpr int Hn  = 128;
constexpr int Cn  = 5;

// float64 values of np.exp(-1/10), np.exp(-1/20)
#define D1 0.9048374180359595731642491
#define D2 0.9512294245007140090914253

typedef double double4_t __attribute__((ext_vector_type(4)));

// ---------------------------------------------------------------------------
// W1 f32 -> f64 into workspace (1024*128 = 131072 elements)
// ---------------------------------------------------------------------------
__global__ __launch_bounds__(256) void cvt_w1(const float* __restrict__ W1,
                                              double* __restrict__ W1d)
{
  const int i = (blockIdx.x * 256 + threadIdx.x) * 4;
  float4 v = *(const float4*)(W1 + i);
  double2 a, b;
  a.x = (double)v.x; a.y = (double)v.y;
  b.x = (double)v.z; b.y = (double)v.w;
  *(double2*)(W1d + i)     = a;
  *(double2*)(W1d + i + 2) = b;
}

// ---------------------------------------------------------------------------
// Phase 1 (MFMA f64): Hc[r,128] = X[row(r),1024] @ W1[1024,128]
// Block: 256 thr (4 waves). TILE_M=16; block covers 64 N-cols (nh half),
// each wave one 16x16 tile. A panel staged f32 in LDS [k][m] (KC=512),
// B read directly from W1d (f64, L2-resident).
// D-fragment layout is SELF-CALIBRATED via a probe MFMA computing
// D[i][j] = 16*i + j; each lane decodes (row,col) per acc register. This is
// immune to any D permutation (incl. reg interleave / operand-role swap).
// ---------------------------------------------------------------------------
constexpr int TILE_M = 16;
constexpr int KC     = 512;
constexpr int APAD   = 17;

__global__ __launch_bounds__(256) void gemm_mfma_f64(
    const float* __restrict__ X, const double* __restrict__ W1d,
    double* __restrict__ Hc, int t0, int Tc)
{
  __shared__ float As[KC][APAD];      // [k][m], 512*17*4 = 34816 B

  const int tid = threadIdx.x;
  const int mt  = blockIdx.x >> 1;    // m-tile index
  const int nh  = blockIdx.x & 1;     // N half (64 cols)
  const int m0  = mt * TILE_M;

  // staging: thread t -> A row rA=t>>4, float4 column group c4=t&15 (+ j*16)
  const int rA = tid >> 4;
  const int c4 = tid & 15;
  const int rc   = m0 + rA;
  const int bidx = rc / Tc;
  const int tl   = rc - bidx * Tc;
  const int grow = bidx * Tn + t0 + tl;
  const float* Apt = X + (size_t)grow * Dn;

  // compute: wave w -> n-tile cols n0..n0+15
  const int w    = tid >> 6;
  const int lane = tid & 63;
  const int mA   = lane & 15;         // A row / B col index supplied
  const int kq   = lane >> 4;         // k index supplied (0..3)
  const int n0   = nh * 64 + w * 16;

  // --- D-layout probe: D[i][j] = 16*i + j ------------------------------
  // A[i][0]=16i, A[i][1]=1; B[0][j]=1, B[1][j]=j  (rank-2, exact ints)
  int drow[4], dcol[4];
  {
    const double ap = (kq == 0) ? (double)(16 * mA) : (kq == 1 ? 1.0 : 0.0);
    const double bp = (kq == 0) ? 1.0 : (kq == 1 ? (double)mA : 0.0);
    double4_t pz = {0.0, 0.0, 0.0, 0.0};
    pz = __builtin_amdgcn_mfma_f64_16x16x4f64(ap, bp, pz, 0, 0, 0);
    #pragma unroll
    for (int r = 0; r < 4; ++r) {
      const int p = (int)pz[r];
      drow[r] = p >> 4;
      dcol[r] = p & 15;
    }
  }

  double4_t acc = {0.0, 0.0, 0.0, 0.0};

  for (int kc = 0; kc < Dn; kc += KC) {
    __syncthreads();
    // stage 16 rows x 512 cols f32 into As[k][m]
    #pragma unroll
    for (int j = 0; j < 8; ++j) {
      const int f = c4 + j * 16;              // float4 index within chunk
      float4 v = *(const float4*)(Apt + kc + 4 * f);
      As[4*f + 0][rA] = v.x;
      As[4*f + 1][rA] = v.y;
      As[4*f + 2][rA] = v.z;
      As[4*f + 3][rA] = v.w;
    }
    __syncthreads();

    const double* bp = W1d + (size_t)(kc + kq) * Hn + n0 + mA;
    #pragma unroll 8
    for (int k0 = 0; k0 < KC; k0 += 4) {
      const double a = (double)As[k0 + kq][mA];
      const double b = bp[(size_t)k0 * Hn];
      acc = __builtin_amdgcn_mfma_f64_16x16x4f64(a, b, acc, 0, 0, 0);
    }
  }

  // epilogue via self-calibrated mapping
  #pragma unroll
  for (int r = 0; r < 4; ++r)
    Hc[(size_t)(m0 + drow[r]) * Hn + n0 + dcol[r]] = acc[r];
}

// ---------------------------------------------------------------------------
// Phase 2: per-batch-row LIF scan over t in [t0, t0+Tc), fp64 state in ws.
// One 64-lane wave per batch row; each lane owns 2 hidden neurons.
// ---------------------------------------------------------------------------
__global__ __launch_bounds__(64) void snn_scan_f64(
    const double* __restrict__ Hc, const float* __restrict__ b1,
    const float* __restrict__ W2, const float* __restrict__ b2,
    double* __restrict__ v1s, double* __restrict__ v2s,
    double* __restrict__ accs, float* __restrict__ out, int t0, int Tc)
{
#pragma clang fp contract(off)
  const int b    = blockIdx.x;
  const int lane = threadIdx.x;
  const int j0   = lane * 2;

  double w2a[Cn], w2b[Cn], bb2[Cn];
  #pragma unroll
  for (int c = 0; c < Cn; ++c) {
    w2a[c] = (double)W2[(size_t)j0 * Cn + c];
    w2b[c] = (double)W2[(size_t)(j0 + 1) * Cn + c];
    bb2[c] = (double)b2[c];
  }
  const double b1a = (double)b1[j0];
  const double b1b = (double)b1[j0 + 1];

  double v1a, v1b, v2[Cn], acc[Cn];
  if (t0 == 0) {
    v1a = 0.0; v1b = 0.0;
    #pragma unroll
    for (int c = 0; c < Cn; ++c) { v2[c] = 0.0; acc[c] = 0.0; }
  } else {
    v1a = v1s[(size_t)b * Hn + j0];
    v1b = v1s[(size_t)b * Hn + j0 + 1];
    #pragma unroll
    for (int c = 0; c < Cn; ++c) {
      v2[c]  = v2s[(size_t)b * Cn + c];
      acc[c] = accs[(size_t)b * Cn + c];
    }
  }

  const double* hp = Hc + (size_t)b * Tc * Hn + j0;
  double2 hnext = *(const double2*)hp;

  for (int t = 0; t < Tc; ++t) {
    const double2 hc = hnext;
    const int tn = (t + 1 < Tc) ? (t + 1) : t;
    hnext = *(const double2*)(hp + (size_t)tn * Hn);

    // v1 = (v1*d1 + h) + b1  (left-assoc, separate roundings)
    v1a = (v1a * D1 + hc.x) + b1a;
    v1b = (v1b * D1 + hc.y) + b1b;
    const double s1a = (v1a >= 1.0) ? 1.0 : 0.0;
    const double s1b = (v1b >= 1.0) ? 1.0 : 0.0;
    v1a = (v1a >= 1.0) ? 0.0 : v1a;
    v1b = (v1b >= 1.0) ? 0.0 : v1b;

    // p[c] = sum_j s1[j] * W2[j,c]  (fp64 butterfly)
    double p[Cn];
    #pragma unroll
    for (int c = 0; c < Cn; ++c)
      p[c] = s1a * w2a[c] + s1b * w2b[c];
    #pragma unroll
    for (int off = 32; off > 0; off >>= 1) {
      #pragma unroll
      for (int c = 0; c < Cn; ++c)
        p[c] += __shfl_xor(p[c], off);
    }

    // v2 = ((v2*d2) + p) + b2
    #pragma unroll
    for (int c = 0; c < Cn; ++c) {
      const double v = ((v2[c] * D2) + p[c]) + bb2[c];
      const double s2 = (v >= 1.0) ? 1.0 : 0.0;
      v2[c]  = (v >= 1.0) ? 0.0 : v;
      acc[c] += s2;
    }
  }

  // persist state for next chunk
  v1s[(size_t)b * Hn + j0]     = v1a;
  v1s[(size_t)b * Hn + j0 + 1] = v1b;
  if (lane == 0) {
    #pragma unroll
    for (int c = 0; c < Cn; ++c) {
      v2s[(size_t)b * Cn + c]  = v2[c];
      accs[(size_t)b * Cn + c] = acc[c];
    }
    if (t0 + Tc == Tn) {
      #pragma unroll
      for (int c = 0; c < Cn; ++c)
        out[(size_t)b * Cn + c] = (float)(acc[c] / 100.0);
    }
  }
}

// ---------------------------------------------------------------------------
extern "C" void kernel_launch(void* const* d_in, const int* in_sizes, int n_in,
                              void* d_out, int out_size, void* d_ws, size_t ws_size,
                              hipStream_t stream) {
  const float* X  = (const float*)d_in[0];   // [B,T,D]
  const float* W1 = (const float*)d_in[1];   // [D,H]
  const float* b1 = (const float*)d_in[2];   // [H]
  const float* W2 = (const float*)d_in[3];   // [H,C]
  const float* b2 = (const float*)d_in[4];   // [C]
  float* out = (float*)d_out;                // [B,C]

  // ws layout: W1d (1 MB) | Hc [B*Tc,H] | v1s | v2s | accs   (all f64)
  const size_t w1Doubles    = (size_t)Dn * Hn;                    // 131072
  const size_t stateDoubles = (size_t)Bsz * Hn + 2 * (size_t)Bsz * Cn;
  static const int cands[] = {100, 50, 25, 20, 10, 5, 4, 2, 1};
  int Tc = 1;
  for (int i = 0; i < 9; ++i) {
    const size_t need =
        (w1Doubles + (size_t)Bsz * cands[i] * Hn + stateDoubles) * sizeof(double);
    if (need <= ws_size) { Tc = cands[i]; break; }
  }

  double* W1d  = (double*)d_ws;
  double* Hc   = W1d + w1Doubles;                    // [B*Tc, H]
  double* v1s  = Hc  + (size_t)Bsz * Tc * Hn;        // [B, H]
  double* v2s  = v1s + (size_t)Bsz * Hn;             // [B, C]
  double* accs = v2s + (size_t)Bsz * Cn;             // [B, C]

  cvt_w1<<<dim3((Dn * Hn) / (256 * 4)), dim3(256), 0, stream>>>(W1, W1d);

  for (int t0 = 0; t0 < Tn; t0 += Tc) {
    const int rows = Bsz * Tc;
    gemm_mfma_f64<<<dim3((rows / TILE_M) * 2), dim3(256), 0, stream>>>(
        X, W1d, Hc, t0, Tc);
    snn_scan_f64<<<dim3(Bsz), dim3(64), 0, stream>>>(Hc, b1, W2, b2,
                                                     v1s, v2s, accs, out, t0, Tc);
  }
}